// Round 1
// baseline (247.673 us; speedup 1.0000x reference)
//
#include <hip/hip_runtime.h>

// Cost volume: out[b,d,h,w] = (w>=d) ? (1/32) * sum_c L[b,c,h,w]*R[b,c,h,w-d] : 0
// B=4, C=32, H=256, W=512, D=64, fp32.
//
// Strategy: 1 workgroup per (b,h) row. R row staged in LDS with 64-float
// zero pad per channel (zero pad makes the w<d masking automatic).
// Each thread: WT=4 x DT=16 output tile, register-blocked; per c-iter:
// 1 global dwordx4 (L) + 5 ds_read_b128 (R window) + 64 v_fma_f32.

constexpr int Bn = 4, Cn = 32, Hn = 256, Wn = 512, Dn = 64;
constexpr int WT = 4, DT = 16;
constexpr int PAD = 64;
constexpr int STRIDE = PAD + Wn;   // 576 floats per channel in LDS
constexpr int HW = Hn * Wn;        // 131072 (power of 2 -> shifts)

__global__ __launch_bounds__(512, 4)
void cost_volume_kernel(const float* __restrict__ left,
                        const float* __restrict__ right,
                        float* __restrict__ out)
{
    __shared__ __align__(16) float Rs[Cn * STRIDE];   // 72 KB

    const int tid = threadIdx.x;
    const int bh  = blockIdx.x;
    const int b   = bh >> 8;          // H = 256
    const int h   = bh & (Hn - 1);

    const float* Lrow = left  + (b * Cn * Hn + h) * Wn;   // channel stride = HW
    const float* Rrow = right + (b * Cn * Hn + h) * Wn;

    // --- zero the left pad: 32 channels x 64 floats = 512 float4, 1/thread
    {
        const int c  = tid >> 4;            // 0..31
        const int wq = (tid & 15) << 2;     // 0..60
        *reinterpret_cast<float4*>(&Rs[c * STRIDE + wq]) =
            make_float4(0.f, 0.f, 0.f, 0.f);
    }

    // --- stage R row into LDS: 32x512 floats = 4096 float4, 8/thread, coalesced
    #pragma unroll
    for (int k = 0; k < 8; ++k) {
        const int f = tid + (k << 9);       // float4 index, 0..4095
        const int c = f >> 7;               // 128 float4 per channel row
        const int w = (f & 127) << 2;
        const float4 v = *reinterpret_cast<const float4*>(&Rrow[c * HW + w]);
        *reinterpret_cast<float4*>(&Rs[c * STRIDE + PAD + w]) = v;
    }
    __syncthreads();

    // --- thread tile: tw in [0,128) covers w, td in [0,4) covers d
    const int tw = tid & 127;
    const int td = tid >> 7;
    const int w0 = tw << 2;                 // WT=4
    const int d0 = td << 4;                 // DT=16
    const int rbase = PAD + w0 - d0 - 16;   // min 0 (tw=0, td=3), multiple of 4

    float acc[DT][WT];
    #pragma unroll
    for (int j = 0; j < DT; ++j)
        #pragma unroll
        for (int i = 0; i < WT; ++i)
            acc[j][i] = 0.f;

    for (int c = 0; c < Cn; ++c) {
        const float4 Lv = *reinterpret_cast<const float4*>(&Lrow[c * HW + w0]);
        const float lv[4] = {Lv.x, Lv.y, Lv.z, Lv.w};

        const float* rp = &Rs[c * STRIDE + rbase];
        float r[20];                        // window R[w0-d0-16 .. w0-d0+3]
        #pragma unroll
        for (int q = 0; q < 5; ++q)
            *reinterpret_cast<float4*>(&r[q * 4]) =
                *reinterpret_cast<const float4*>(&rp[q * 4]);

        // acc[j][i] += L[c][w0+i] * R[c][w0+i - (d0+j)]  -> r[16 + i - j], in [1,19]
        #pragma unroll
        for (int j = 0; j < DT; ++j)
            #pragma unroll
            for (int i = 0; i < WT; ++i)
                acc[j][i] = fmaf(lv[i], r[16 + i - j], acc[j][i]);
    }

    // --- epilogue: out[b][d0+j][h][w0..w0+3], coalesced dwordx4 per j
    constexpr float inv = 1.0f / 32.0f;
    float* op = out + ((b * Dn + d0) * Hn + h) * Wn + w0;
    #pragma unroll
    for (int j = 0; j < DT; ++j) {
        const float4 v = make_float4(acc[j][0] * inv, acc[j][1] * inv,
                                     acc[j][2] * inv, acc[j][3] * inv);
        *reinterpret_cast<float4*>(&op[j * HW]) = v;
    }
}

extern "C" void kernel_launch(void* const* d_in, const int* in_sizes, int n_in,
                              void* d_out, int out_size, void* d_ws, size_t ws_size,
                              hipStream_t stream) {
    const float* left  = (const float*)d_in[0];
    const float* right = (const float*)d_in[1];
    float* out = (float*)d_out;
    cost_volume_kernel<<<dim3(Bn * Hn), dim3(512), 0, stream>>>(left, right, out);
}